// Round 15
// baseline (61.431 us; speedup 1.0000x reference)
//
#include <hip/hip_runtime.h>

#define HH   48
#define WW   96
#define CC   256
#define RRAD 4
#define DD   9
#define DD2  81
#define PP   10
#define HWSZ (HH * WW)              // 4608
#define ROWB 512                    // bytes per bf16 channel row (256*2)
#define ZOFF ((unsigned)HWSZ * ROWB) // zero page offset from f2tb base

typedef __attribute__((ext_vector_type(8))) short short8v;  // 8 bf16 (4 VGPRs)
typedef __attribute__((ext_vector_type(4))) float f32x4;

__device__ __forceinline__ unsigned bf16rne(float f) {      // RNE f32->bf16 bits
  unsigned u = __float_as_uint(f);
  return (u + 0x7FFFu + ((u >> 16) & 1u)) >> 16;
}

// ---------------- kernel 1: transposes + W-prep (fragment-major) ----------------
__global__ __launch_bounds__(256) void transpose_to_bf16(
    const float* __restrict__ f1, const float* __restrict__ f2,
    const float* __restrict__ w_dap, char* __restrict__ f2tb,
    char* __restrict__ f1tb, char* __restrict__ zpage,
    unsigned short* __restrict__ Wf) {
  __shared__ float tile[64][65];
  const float* src = (blockIdx.y == 0) ? f1 : f2;
  char* dst = (blockIdx.y == 0) ? f1tb : f2tb;

  const int tid = threadIdx.x;
  if (blockIdx.y == 0 && blockIdx.x == 0 && tid < 32) {   // zero the 512 B zero page
    float4 z = {0.f, 0.f, 0.f, 0.f};
    *(float4*)(zpage + tid * 16) = z;
  }
  if (blockIdx.y == 0 && blockIdx.x < 36) {   // W-prep: 9216 shorts over 36 blocks
    int gid = blockIdx.x * 256 + tid;
    int g = gid >> 9;                         // (m,kt) group 0..17
    int idx = gid & 511;
    int ln = idx >> 3, e = idx & 7;
    int m = g / 3, kt = g - m * 3;
    int r = m * 16 + (ln & 15);
    int c = kt * 32 + (ln >> 4) * 8 + e;
    float v = (r < DD2 && c < DD2) ? w_dap[r * DD2 + c] : 0.f;
    Wf[gid] = (unsigned short)bf16rne(v);
  }

  const int tiles_p = HWSZ / 64;              // 72
  const int bc = blockIdx.x / tiles_p;        // channel tile 0..3
  const int bp = blockIdx.x % tiles_p;        // pixel tile 0..71
  const int c0 = bc * 64, p0 = bp * 64;

#pragma unroll
  for (int k = 0; k < 16; k++) {
    int idx = k * 256 + tid;
    int cl = idx >> 6, pl = idx & 63;         // coalesced over pixels
    tile[cl][pl] = src[(size_t)(c0 + cl) * HWSZ + p0 + pl];
  }
  __syncthreads();
#pragma unroll
  for (int k = 0; k < 8; k++) {               // pack 2 channels -> 4 B stores
    int idx = k * 256 + tid;
    int pl = idx >> 5, cp = idx & 31;
    unsigned lo = bf16rne(tile[2 * cp][pl]);
    unsigned hi = bf16rne(tile[2 * cp + 1][pl]);
    *(unsigned*)(dst + (size_t)(p0 + pl) * ROWB + (size_t)c0 * 2 + cp * 4) =
        lo | (hi << 16);
  }
}

// ---------------- kernel 2: REG-STAGED corr -> cbg[p][96] bf16 ----------------
// Swizzle discipline (rule #21): global load LINEAR (contiguous 512B runs),
// LDS WRITE carries the XOR swizzle, LDS read applies the same XOR.
// (R14 bug: swizzle on load-addr AND write-addr cancelled -> scrambled reads.)
// Per-wave self-contained: wave w stages+consumes tiles {w, w+4}; within-wave
// DS in-order pipe -> no barriers/waitcnts until the dots reduction.
__global__ __launch_bounds__(256, 3) void corr_main(
    const char* __restrict__ f2tb, const char* __restrict__ f1tb,
    const float* __restrict__ coords, unsigned short* __restrict__ cbg) {
  __shared__ __align__(16) char patch[100 * ROWB];  // 51200 B, XOR-swizzled
  __shared__ float dots[112];

  const int p = blockIdx.x;
  const int tid = threadIdx.x;
  const int lane = tid & 63, wid = tid >> 6;
  const int hi = lane >> 4, lo = lane & 15;
  const int sub = lane >> 5;                  // row within a chunk pair
  const int col = (lane & 31) * 16;           // byte within row

  const float cx = coords[p];
  const float cy = coords[HWSZ + p];
  const float fxf = floorf(cx), fyf = floorf(cy);
  const float fx = cx - fxf, fy = cy - fyf;
  const int xb = (int)fxf - RRAD;
  const int yb = (int)fyf - RRAD;

  // B fragments: direct from global (4 distinct 16B per instr, merge-friendly)
  const char* f1b = f1tb + (size_t)p * ROWB + hi * 16;
  short8v bfrag[8];
#pragma unroll
  for (int kt = 0; kt < 8; kt++) bfrag[kt] = *(const short8v*)(f1b + kt * 64);

  // ---- stage tiles A (wid) and B (wid+4) into registers (LINEAR loads) ----
  float4 av[8], bv[8];
#pragma unroll
  for (int k = 0; k < 8; k++) {               // tile A: rows wid*16 .. +15
    const int r = wid * 16 + 2 * k + sub;
    const int yy = (r * 205) >> 11;           // r/10 (exact for r<112)
    const int xx = r - yy * 10;
    const int gy = yb + yy, gx = xb + xx;
    const unsigned ro = (gx >= 0 && gx < WW && gy >= 0 && gy < HH)
                            ? (unsigned)(gy * WW + gx) * ROWB : ZOFF;
    av[k] = *(const float4*)(f2tb + ro + col);
  }
  const int tiB = wid + 4;
#pragma unroll
  for (int k = 0; k < 8; k++) {               // tile B: rows (wid+4)*16 .. (cap 100)
    const int basek = tiB * 16 + 2 * k;
    if (basek < 100) {
      const int r = basek + sub;
      const int yy = (r * 205) >> 11;
      const int xx = r - yy * 10;
      const int gy = yb + yy, gx = xb + xx;
      const unsigned ro = (gx >= 0 && gx < WW && gy >= 0 && gy < HH)
                              ? (unsigned)(gy * WW + gx) * ROWB : ZOFF;
      bv[k] = *(const float4*)(f2tb + ro + col);
    }
  }

  // ---- tile A: swizzled ds_write -> swizzled ds_read (own rows; in-order DS) ----
#pragma unroll
  for (int k = 0; k < 8; k++) {
    const int r = wid * 16 + 2 * k + sub;
    *(float4*)(patch + r * ROWB + (col ^ ((r & 7) << 4))) = av[k];
  }
  {
    const int m = wid;
    const int row = m * 16 + lo;
    const char* rp2 = patch + row * ROWB;
    const int swz = (row & 7) << 4;
    short8v a[8];
#pragma unroll
    for (int kt = 0; kt < 8; kt++)
      a[kt] = *(const short8v*)(rp2 + ((hi * 16 + kt * 64) ^ swz));
    f32x4 acc = {0.f, 0.f, 0.f, 0.f};
#pragma unroll
    for (int kt = 0; kt < 8; kt++)
      acc = __builtin_amdgcn_mfma_f32_16x16x32_bf16(a[kt], bfrag[kt], acc, 0, 0, 0);
    if (lo == 0) {
      const int rb = m * 16 + hi * 4;
      dots[rb + 0] = acc[0]; dots[rb + 1] = acc[1];
      dots[rb + 2] = acc[2]; dots[rb + 3] = acc[3];
    }
  }

  // ---- tile B (waves 0-2) ----
  if (wid < 3) {
#pragma unroll
    for (int k = 0; k < 8; k++) {
      const int basek = tiB * 16 + 2 * k;
      if (basek < 100) {
        const int r = basek + sub;
        *(float4*)(patch + r * ROWB + (col ^ ((r & 7) << 4))) = bv[k];
      }
    }
    const int m = tiB;
    int row = m * 16 + lo;
    row = row > 99 ? 99 : row;                // tile-6 tail: dup row, dots discarded
    const char* rp2 = patch + row * ROWB;
    const int swz = (row & 7) << 4;
    short8v a[8];
#pragma unroll
    for (int kt = 0; kt < 8; kt++)
      a[kt] = *(const short8v*)(rp2 + ((hi * 16 + kt * 64) ^ swz));
    f32x4 acc = {0.f, 0.f, 0.f, 0.f};
#pragma unroll
    for (int kt = 0; kt < 8; kt++)
      acc = __builtin_amdgcn_mfma_f32_16x16x32_bf16(a[kt], bfrag[kt], acc, 0, 0, 0);
    if (lo == 0) {
      const int rb = m * 16 + hi * 4;
      dots[rb + 0] = acc[0]; dots[rb + 1] = acc[1];
      dots[rb + 2] = acc[2]; dots[rb + 3] = acc[3];
    }
  }

  __syncthreads();                            // dots ready (vmcnt already drained)

  // 81 bilinear combines -> cbg[p][96] bf16 (192 B contiguous per pixel)
  if (tid < 96) {
    float c = 0.f;
    if (tid < DD2) {
      const int i = tid / DD, j = tid - i * DD;
      const float d00 = dots[j * PP + i];
      const float d01 = dots[j * PP + i + 1];
      const float d10 = dots[(j + 1) * PP + i];
      const float d11 = dots[(j + 1) * PP + i + 1];
      c = ((1.f - fy) * ((1.f - fx) * d00 + fx * d01) +
           fy * ((1.f - fx) * d10 + fx * d11)) * 0.0625f;   // 1/sqrt(256)
    }
    cbg[(size_t)p * 96 + tid] = (unsigned short)bf16rne(c);
  }
}

// ---------------- kernel 3: DAP as batched GEMM  out[96x4608] = W(96x96).CB ----------------
__global__ __launch_bounds__(64) void dap_gemm(
    const unsigned short* __restrict__ cbg, const unsigned short* __restrict__ Wf,
    float* __restrict__ out) {
  const int lane = threadIdx.x;
  const int hi = lane >> 4, lo = lane & 15;
  const int p0 = blockIdx.x * 16;

  short8v bq[3];
#pragma unroll
  for (int kt = 0; kt < 3; kt++)
    bq[kt] = *(const short8v*)(cbg + (size_t)(p0 + lo) * 96 + kt * 32 + hi * 8);

  f32x4 acc[6];
#pragma unroll
  for (int m = 0; m < 6; m++) acc[m] = (f32x4){0.f, 0.f, 0.f, 0.f};

#pragma unroll
  for (int m = 0; m < 6; m++) {
#pragma unroll
    for (int kt = 0; kt < 3; kt++) {
      short8v aw = *(const short8v*)(Wf + ((size_t)(m * 3 + kt) * 64 + lane) * 8);
      acc[m] = __builtin_amdgcn_mfma_f32_16x16x32_bf16(aw, bq[kt], acc[m], 0, 0, 0);
    }
  }

#pragma unroll
  for (int m = 0; m < 6; m++) {
#pragma unroll
    for (int j = 0; j < 4; j++) {
      const int o = m * 16 + hi * 4 + j;
      if (o < DD2) out[(size_t)o * HWSZ + p0 + lo] = acc[m][j];
    }
  }
}

extern "C" void kernel_launch(void* const* d_in, const int* in_sizes, int n_in,
                              void* d_out, int out_size, void* d_ws, size_t ws_size,
                              hipStream_t stream) {
  const float* f1     = (const float*)d_in[0];
  const float* f2     = (const float*)d_in[1];
  const float* coords = (const float*)d_in[2];
  const float* w_dap  = (const float*)d_in[3];
  float* out = (float*)d_out;

  // ws layout: [f2tb: HWSZ*512][zpage: 512][f1tb: HWSZ*512][Wf: 9216*2][cbg: HWSZ*96*2]
  char* f2tb  = (char*)d_ws;
  char* zpage = f2tb + (size_t)HWSZ * ROWB;
  char* f1tb  = zpage + 512;
  unsigned short* Wf  = (unsigned short*)(f1tb + (size_t)HWSZ * ROWB);
  unsigned short* cbg = Wf + 9216;

  dim3 tgrid((CC / 64) * (HWSZ / 64), 2);
  transpose_to_bf16<<<tgrid, 256, 0, stream>>>(f1, f2, w_dap, f2tb, f1tb, zpage, Wf);

  corr_main<<<dim3(HWSZ), 256, 0, stream>>>(f2tb, f1tb, coords, cbg);

  dap_gemm<<<dim3(HWSZ / 16), 64, 0, stream>>>(cbg, Wf, out);
}

// Round 16
// 50.963 us; speedup vs baseline: 1.2054x; 1.2054x over previous
//
#include <hip/hip_runtime.h>

#define HH   48
#define WW   96
#define CC   256
#define RRAD 4
#define DD   9
#define DD2  81
#define PP   10
#define HWSZ (HH * WW)              // 4608
#define ROWB 512                    // bytes per bf16 channel row (256*2)
#define ZOFF ((unsigned)HWSZ * ROWB) // zero page offset from f2tb base

typedef __attribute__((ext_vector_type(8))) short short8v;  // 8 bf16 (4 VGPRs)
typedef __attribute__((ext_vector_type(4))) float f32x4;

__device__ __forceinline__ unsigned bf16rne(float f) {      // RNE f32->bf16 bits
  unsigned u = __float_as_uint(f);
  return (u + 0x7FFFu + ((u >> 16) & 1u)) >> 16;
}

// ---------------- kernel 1: transposes + W-prep (fragment-major) ----------------
__global__ __launch_bounds__(256) void transpose_to_bf16(
    const float* __restrict__ f1, const float* __restrict__ f2,
    const float* __restrict__ w_dap, char* __restrict__ f2tb,
    char* __restrict__ f1tb, char* __restrict__ zpage,
    unsigned short* __restrict__ Wf) {
  __shared__ float tile[64][65];
  const float* src = (blockIdx.y == 0) ? f1 : f2;
  char* dst = (blockIdx.y == 0) ? f1tb : f2tb;

  const int tid = threadIdx.x;
  if (blockIdx.y == 0 && blockIdx.x == 0 && tid < 32) {   // zero the 512 B zero page
    float4 z = {0.f, 0.f, 0.f, 0.f};
    *(float4*)(zpage + tid * 16) = z;
  }
  if (blockIdx.y == 0 && blockIdx.x < 36) {   // W-prep: 9216 shorts over 36 blocks
    int gid = blockIdx.x * 256 + tid;
    int g = gid >> 9;                         // (m,kt) group 0..17
    int idx = gid & 511;
    int ln = idx >> 3, e = idx & 7;
    int m = g / 3, kt = g - m * 3;
    int r = m * 16 + (ln & 15);
    int c = kt * 32 + (ln >> 4) * 8 + e;
    float v = (r < DD2 && c < DD2) ? w_dap[r * DD2 + c] : 0.f;
    Wf[gid] = (unsigned short)bf16rne(v);
  }

  const int tiles_p = HWSZ / 64;              // 72
  const int bc = blockIdx.x / tiles_p;        // channel tile 0..3
  const int bp = blockIdx.x % tiles_p;        // pixel tile 0..71
  const int c0 = bc * 64, p0 = bp * 64;

#pragma unroll
  for (int k = 0; k < 16; k++) {
    int idx = k * 256 + tid;
    int cl = idx >> 6, pl = idx & 63;         // coalesced over pixels
    tile[cl][pl] = src[(size_t)(c0 + cl) * HWSZ + p0 + pl];
  }
  __syncthreads();
#pragma unroll
  for (int k = 0; k < 8; k++) {               // pack 2 channels -> 4 B stores
    int idx = k * 256 + tid;
    int pl = idx >> 5, cp = idx & 31;
    unsigned lo = bf16rne(tile[2 * cp][pl]);
    unsigned hi = bf16rne(tile[2 * cp + 1][pl]);
    *(unsigned*)(dst + (size_t)(p0 + pl) * ROWB + (size_t)c0 * 2 + cp * 4) =
        lo | (hi << 16);
  }
}

// row r -> source byte offset (zero page if out of range)
__device__ __forceinline__ unsigned row_src(int r, int xb, int yb) {
  const int yy = (r * 205) >> 11;             // r/10 (exact for r<112)
  const int xx = r - yy * 10;
  const int gy = yb + yy, gx = xb + xx;
  return (gx >= 0 && gx < WW && gy >= 0 && gy < HH)
             ? (unsigned)(gy * WW + gx) * ROWB : ZOFF;
}

// ---------------- kernel 2: REG-STAGED corr (spill-proof) -> cbg[p][96] bf16 ----------------
// All unrolled staging loops have COMPILE-TIME trip counts (R15's runtime-wid
// bound made bv[] unpromotable -> 83MB scratch spills, rule #20).
// Global loads LINEAR (TA lane-merge: 4 lanes/64B line); XOR swizzle only on
// ds_write + ds_read (rule #21). Per-wave self-contained tiles -> no barrier
// before the dots reduction.
__global__ __launch_bounds__(256, 3) void corr_main(
    const char* __restrict__ f2tb, const char* __restrict__ f1tb,
    const float* __restrict__ coords, unsigned short* __restrict__ cbg) {
  __shared__ __align__(16) char patch[100 * ROWB];  // 51200 B, XOR-swizzled
  __shared__ float dots[112];

  const int p = blockIdx.x;
  const int tid = threadIdx.x;
  const int lane = tid & 63, wid = tid >> 6;
  const int hi = lane >> 4, lo = lane & 15;
  const int sub = lane >> 5;                  // row within a chunk pair
  const int col = (lane & 31) * 16;           // byte within row

  const float cx = coords[p];
  const float cy = coords[HWSZ + p];
  const float fxf = floorf(cx), fyf = floorf(cy);
  const float fx = cx - fxf, fy = cy - fyf;
  const int xb = (int)fxf - RRAD;
  const int yb = (int)fyf - RRAD;

  // B fragments: direct from global (broadcast across 16 lanes -> 1 line-req)
  const char* f1b = f1tb + (size_t)p * ROWB + hi * 16;
  short8v bfrag[8];
#pragma unroll
  for (int kt = 0; kt < 8; kt++) bfrag[kt] = *(const short8v*)(f1b + kt * 64);

  // ---- stage tile A (rows wid*16..+15, always valid) into registers ----
  float4 av[8];
#pragma unroll
  for (int k = 0; k < 8; k++) {
    const int r = wid * 16 + 2 * k + sub;
    av[k] = *(const float4*)(f2tb + row_src(r, xb, yb) + col);
  }
  // ---- stage tile B: waves 0-1 full (rows 64..95), wave 2 rows 96-99 ----
  float4 bv[8];
  if (wid < 2) {
#pragma unroll
    for (int k = 0; k < 8; k++) {
      const int r = (wid + 4) * 16 + 2 * k + sub;
      bv[k] = *(const float4*)(f2tb + row_src(r, xb, yb) + col);
    }
  } else if (wid == 2) {
#pragma unroll
    for (int k = 0; k < 2; k++) {
      const int r = 96 + 2 * k + sub;
      bv[k] = *(const float4*)(f2tb + row_src(r, xb, yb) + col);
    }
  }

  // ---- tile A: swizzled ds_write -> swizzled ds_read -> MFMA ----
#pragma unroll
  for (int k = 0; k < 8; k++) {
    const int r = wid * 16 + 2 * k + sub;
    *(float4*)(patch + r * ROWB + (col ^ ((r & 7) << 4))) = av[k];
  }
  {
    const int m = wid;
    const int row = m * 16 + lo;
    const char* rp2 = patch + row * ROWB;
    const int swz = (row & 7) << 4;
    short8v a[8];
#pragma unroll
    for (int kt = 0; kt < 8; kt++)
      a[kt] = *(const short8v*)(rp2 + ((hi * 16 + kt * 64) ^ swz));
    f32x4 acc = {0.f, 0.f, 0.f, 0.f};
#pragma unroll
    for (int kt = 0; kt < 8; kt++)
      acc = __builtin_amdgcn_mfma_f32_16x16x32_bf16(a[kt], bfrag[kt], acc, 0, 0, 0);
    if (lo == 0) {
      const int rb = m * 16 + hi * 4;
      dots[rb + 0] = acc[0]; dots[rb + 1] = acc[1];
      dots[rb + 2] = acc[2]; dots[rb + 3] = acc[3];
    }
  }

  // ---- tile B ----
  if (wid < 2) {
#pragma unroll
    for (int k = 0; k < 8; k++) {
      const int r = (wid + 4) * 16 + 2 * k + sub;
      *(float4*)(patch + r * ROWB + (col ^ ((r & 7) << 4))) = bv[k];
    }
    const int m = wid + 4;
    const int row = m * 16 + lo;
    const char* rp2 = patch + row * ROWB;
    const int swz = (row & 7) << 4;
    short8v a[8];
#pragma unroll
    for (int kt = 0; kt < 8; kt++)
      a[kt] = *(const short8v*)(rp2 + ((hi * 16 + kt * 64) ^ swz));
    f32x4 acc = {0.f, 0.f, 0.f, 0.f};
#pragma unroll
    for (int kt = 0; kt < 8; kt++)
      acc = __builtin_amdgcn_mfma_f32_16x16x32_bf16(a[kt], bfrag[kt], acc, 0, 0, 0);
    if (lo == 0) {
      const int rb = m * 16 + hi * 4;
      dots[rb + 0] = acc[0]; dots[rb + 1] = acc[1];
      dots[rb + 2] = acc[2]; dots[rb + 3] = acc[3];
    }
  } else if (wid == 2) {
#pragma unroll
    for (int k = 0; k < 2; k++) {
      const int r = 96 + 2 * k + sub;
      *(float4*)(patch + r * ROWB + (col ^ ((r & 7) << 4))) = bv[k];
    }
    const int m = 6;                          // rows 96..111, clamp to 99
    int row = m * 16 + lo;
    row = row > 99 ? 99 : row;
    const char* rp2 = patch + row * ROWB;
    const int swz = (row & 7) << 4;
    short8v a[8];
#pragma unroll
    for (int kt = 0; kt < 8; kt++)
      a[kt] = *(const short8v*)(rp2 + ((hi * 16 + kt * 64) ^ swz));
    f32x4 acc = {0.f, 0.f, 0.f, 0.f};
#pragma unroll
    for (int kt = 0; kt < 8; kt++)
      acc = __builtin_amdgcn_mfma_f32_16x16x32_bf16(a[kt], bfrag[kt], acc, 0, 0, 0);
    if (lo == 0) {
      const int rb = m * 16 + hi * 4;
      dots[rb + 0] = acc[0]; dots[rb + 1] = acc[1];
      dots[rb + 2] = acc[2]; dots[rb + 3] = acc[3];
    }
  }

  __syncthreads();                            // dots ready

  // 81 bilinear combines -> cbg[p][96] bf16 (192 B contiguous per pixel)
  if (tid < 96) {
    float c = 0.f;
    if (tid < DD2) {
      const int i = tid / DD, j = tid - i * DD;
      const float d00 = dots[j * PP + i];
      const float d01 = dots[j * PP + i + 1];
      const float d10 = dots[(j + 1) * PP + i];
      const float d11 = dots[(j + 1) * PP + i + 1];
      c = ((1.f - fy) * ((1.f - fx) * d00 + fx * d01) +
           fy * ((1.f - fx) * d10 + fx * d11)) * 0.0625f;   // 1/sqrt(256)
    }
    cbg[(size_t)p * 96 + tid] = (unsigned short)bf16rne(c);
  }
}

// ---------------- kernel 3: DAP as batched GEMM  out[96x4608] = W(96x96).CB ----------------
__global__ __launch_bounds__(64) void dap_gemm(
    const unsigned short* __restrict__ cbg, const unsigned short* __restrict__ Wf,
    float* __restrict__ out) {
  const int lane = threadIdx.x;
  const int hi = lane >> 4, lo = lane & 15;
  const int p0 = blockIdx.x * 16;

  short8v bq[3];
#pragma unroll
  for (int kt = 0; kt < 3; kt++)
    bq[kt] = *(const short8v*)(cbg + (size_t)(p0 + lo) * 96 + kt * 32 + hi * 8);

  f32x4 acc[6];
#pragma unroll
  for (int m = 0; m < 6; m++) acc[m] = (f32x4){0.f, 0.f, 0.f, 0.f};

#pragma unroll
  for (int m = 0; m < 6; m++) {
#pragma unroll
    for (int kt = 0; kt < 3; kt++) {
      short8v aw = *(const short8v*)(Wf + ((size_t)(m * 3 + kt) * 64 + lane) * 8);
      acc[m] = __builtin_amdgcn_mfma_f32_16x16x32_bf16(aw, bq[kt], acc[m], 0, 0, 0);
    }
  }

#pragma unroll
  for (int m = 0; m < 6; m++) {
#pragma unroll
    for (int j = 0; j < 4; j++) {
      const int o = m * 16 + hi * 4 + j;
      if (o < DD2) out[(size_t)o * HWSZ + p0 + lo] = acc[m][j];
    }
  }
}

extern "C" void kernel_launch(void* const* d_in, const int* in_sizes, int n_in,
                              void* d_out, int out_size, void* d_ws, size_t ws_size,
                              hipStream_t stream) {
  const float* f1     = (const float*)d_in[0];
  const float* f2     = (const float*)d_in[1];
  const float* coords = (const float*)d_in[2];
  const float* w_dap  = (const float*)d_in[3];
  float* out = (float*)d_out;

  // ws layout: [f2tb: HWSZ*512][zpage: 512][f1tb: HWSZ*512][Wf: 9216*2][cbg: HWSZ*96*2]
  char* f2tb  = (char*)d_ws;
  char* zpage = f2tb + (size_t)HWSZ * ROWB;
  char* f1tb  = zpage + 512;
  unsigned short* Wf  = (unsigned short*)(f1tb + (size_t)HWSZ * ROWB);
  unsigned short* cbg = Wf + 9216;

  dim3 tgrid((CC / 64) * (HWSZ / 64), 2);
  transpose_to_bf16<<<tgrid, 256, 0, stream>>>(f1, f2, w_dap, f2tb, f1tb, zpage, Wf);

  corr_main<<<dim3(HWSZ), 256, 0, stream>>>(f2tb, f1tb, coords, cbg);

  dap_gemm<<<dim3(HWSZ / 16), 64, 0, stream>>>(cbg, Wf, out);
}

// Round 17
// 35.317 us; speedup vs baseline: 1.7394x; 1.4430x over previous
//
#include <hip/hip_runtime.h>

#define HH   48
#define WW   96
#define CC   256
#define RRAD 4
#define DD   9
#define DD2  81
#define PP   10
#define HWSZ (HH * WW)              // 4608
#define ROWB 512                    // bytes per bf16 channel row (256*2)
#define ZOFF ((unsigned)HWSZ * ROWB) // zero page offset from f2tb base

typedef __attribute__((ext_vector_type(8))) short short8v;  // 8 bf16 (4 VGPRs)
typedef __attribute__((ext_vector_type(4))) float f32x4;

__device__ __forceinline__ unsigned bf16rne(float f) {      // RNE f32->bf16 bits
  unsigned u = __float_as_uint(f);
  return (u + 0x7FFFu + ((u >> 16) & 1u)) >> 16;
}

// ---------------- kernel 1: transposes + W-prep (fragment-major) ----------------
__global__ __launch_bounds__(256) void transpose_to_bf16(
    const float* __restrict__ f1, const float* __restrict__ f2,
    const float* __restrict__ w_dap, char* __restrict__ f2tb,
    char* __restrict__ f1tb, char* __restrict__ zpage,
    unsigned short* __restrict__ Wf) {
  __shared__ float tile[64][65];
  const float* src = (blockIdx.y == 0) ? f1 : f2;
  char* dst = (blockIdx.y == 0) ? f1tb : f2tb;

  const int tid = threadIdx.x;
  if (blockIdx.y == 0 && blockIdx.x == 0 && tid < 32) {   // zero the 512 B zero page
    float4 z = {0.f, 0.f, 0.f, 0.f};
    *(float4*)(zpage + tid * 16) = z;
  }
  if (blockIdx.y == 0 && blockIdx.x < 36) {   // W-prep: 9216 shorts over 36 blocks
    int gid = blockIdx.x * 256 + tid;
    int g = gid >> 9;                         // (m,kt) group 0..17
    int idx = gid & 511;
    int ln = idx >> 3, e = idx & 7;
    int m = g / 3, kt = g - m * 3;
    int r = m * 16 + (ln & 15);
    int c = kt * 32 + (ln >> 4) * 8 + e;
    float v = (r < DD2 && c < DD2) ? w_dap[r * DD2 + c] : 0.f;
    Wf[gid] = (unsigned short)bf16rne(v);
  }

  const int tiles_p = HWSZ / 64;              // 72
  const int bc = blockIdx.x / tiles_p;        // channel tile 0..3
  const int bp = blockIdx.x % tiles_p;        // pixel tile 0..71
  const int c0 = bc * 64, p0 = bp * 64;

#pragma unroll
  for (int k = 0; k < 16; k++) {
    int idx = k * 256 + tid;
    int cl = idx >> 6, pl = idx & 63;         // coalesced over pixels
    tile[cl][pl] = src[(size_t)(c0 + cl) * HWSZ + p0 + pl];
  }
  __syncthreads();
#pragma unroll
  for (int k = 0; k < 8; k++) {               // pack 2 channels -> 4 B stores
    int idx = k * 256 + tid;
    int pl = idx >> 5, cp = idx & 31;
    unsigned lo = bf16rne(tile[2 * cp][pl]);
    unsigned hi = bf16rne(tile[2 * cp + 1][pl]);
    *(unsigned*)(dst + (size_t)(p0 + pl) * ROWB + (size_t)c0 * 2 + cp * 4) =
        lo | (hi << 16);
  }
}

// row r -> source byte offset (zero page if out of range)
__device__ __forceinline__ unsigned row_src(int r, int xb, int yb) {
  const int yy = (r * 205) >> 11;             // r/10 (exact for r<112)
  const int xx = r - yy * 10;
  const int gy = yb + yy, gx = xb + xx;
  return (gx >= 0 && gx < WW && gy >= 0 && gy < HH)
             ? (unsigned)(gy * WW + gx) * ROWB : ZOFF;
}

// ---------------- kernel 2: REG-STAGED corr -> cbg[p][96] bf16 ----------------
// Spill discipline: each staged array's ENTIRE life (load -> ds_write) is one
// straight-line region; nothing staged lives across a divergent-region
// boundary (R15/R16: cross-region liveness under exec-mask divergence demoted
// av/bv to scratch -> 83MB spill traffic at VGPR_Count=68).
// Global loads LINEAR (32-lane half = contiguous 512B -> TA lane-merge);
// XOR swizzle only on ds_write + ds_read (rule #21). Per-wave-owned rows ->
// no barrier before the dots reduction.
__global__ __launch_bounds__(256, 3) void corr_main(
    const char* __restrict__ f2tb, const char* __restrict__ f1tb,
    const float* __restrict__ coords, unsigned short* __restrict__ cbg) {
  __shared__ __align__(16) char patch[100 * ROWB];  // 51200 B, XOR-swizzled
  __shared__ float dots[112];

  const int p = blockIdx.x;
  const int tid = threadIdx.x;
  const int lane = tid & 63, wid = tid >> 6;
  const int hi = lane >> 4, lo = lane & 15;
  const int sub = lane >> 5;                  // row within a chunk pair
  const int col = (lane & 31) * 16;           // byte within row

  const float cx = coords[p];
  const float cy = coords[HWSZ + p];
  const float fxf = floorf(cx), fyf = floorf(cy);
  const float fx = cx - fxf, fy = cy - fyf;
  const int xb = (int)fxf - RRAD;
  const int yb = (int)fyf - RRAD;

  // ---- phase 1: tile A (rows wid*16..+15) load+write, one region ----
  {
    float4 av[8];
#pragma unroll
    for (int k = 0; k < 8; k++) {
      const int r = wid * 16 + 2 * k + sub;
      av[k] = *(const float4*)(f2tb + row_src(r, xb, yb) + col);
    }
#pragma unroll
    for (int k = 0; k < 8; k++) {
      const int r = wid * 16 + 2 * k + sub;
      *(float4*)(patch + r * ROWB + (col ^ ((r & 7) << 4))) = av[k];
    }
  }

  // ---- phase 2: tile B load+write, single branch region each ----
  if (wid < 2) {                              // tiles 4,5: rows 64..95
    float4 bv[8];
#pragma unroll
    for (int k = 0; k < 8; k++) {
      const int r = 64 + wid * 16 + 2 * k + sub;
      bv[k] = *(const float4*)(f2tb + row_src(r, xb, yb) + col);
    }
#pragma unroll
    for (int k = 0; k < 8; k++) {
      const int r = 64 + wid * 16 + 2 * k + sub;
      *(float4*)(patch + r * ROWB + (col ^ ((r & 7) << 4))) = bv[k];
    }
  } else if (wid == 2) {                      // tile 6: real rows 96..99
    float4 b0 = *(const float4*)(f2tb + row_src(96 + sub, xb, yb) + col);
    float4 b1 = *(const float4*)(f2tb + row_src(98 + sub, xb, yb) + col);
    const int r0 = 96 + sub, r1 = 98 + sub;
    *(float4*)(patch + r0 * ROWB + (col ^ ((r0 & 7) << 4))) = b0;
    *(float4*)(patch + r1 * ROWB + (col ^ ((r1 & 7) << 4))) = b1;
  }

  // ---- phase 3: B fragments from global (broadcast-friendly) ----
  const char* f1b = f1tb + (size_t)p * ROWB + hi * 16;
  short8v bfrag[8];
#pragma unroll
  for (int kt = 0; kt < 8; kt++) bfrag[kt] = *(const short8v*)(f1b + kt * 64);

  // ---- phase 4: MFMA tile A ----
  {
    const int m = wid;
    const int row = m * 16 + lo;
    const char* rp2 = patch + row * ROWB;
    const int swz = (row & 7) << 4;
    short8v a[8];
#pragma unroll
    for (int kt = 0; kt < 8; kt++)
      a[kt] = *(const short8v*)(rp2 + ((hi * 16 + kt * 64) ^ swz));
    f32x4 acc = {0.f, 0.f, 0.f, 0.f};
#pragma unroll
    for (int kt = 0; kt < 8; kt++)
      acc = __builtin_amdgcn_mfma_f32_16x16x32_bf16(a[kt], bfrag[kt], acc, 0, 0, 0);
    if (lo == 0) {
      const int rb = m * 16 + hi * 4;
      dots[rb + 0] = acc[0]; dots[rb + 1] = acc[1];
      dots[rb + 2] = acc[2]; dots[rb + 3] = acc[3];
    }
  }

  // ---- phase 5: MFMA tile B (waves 0-2; wave2 = tile 6 with clamp) ----
  if (wid < 3) {
    const int m = wid + 4;
    int row = m * 16 + lo;
    row = row > 99 ? 99 : row;                // tile-6 tail: dup row, dots discarded
    const char* rp2 = patch + row * ROWB;
    const int swz = (row & 7) << 4;
    short8v a[8];
#pragma unroll
    for (int kt = 0; kt < 8; kt++)
      a[kt] = *(const short8v*)(rp2 + ((hi * 16 + kt * 64) ^ swz));
    f32x4 acc = {0.f, 0.f, 0.f, 0.f};
#pragma unroll
    for (int kt = 0; kt < 8; kt++)
      acc = __builtin_amdgcn_mfma_f32_16x16x32_bf16(a[kt], bfrag[kt], acc, 0, 0, 0);
    if (lo == 0) {
      const int rb = m * 16 + hi * 4;
      dots[rb + 0] = acc[0]; dots[rb + 1] = acc[1];
      dots[rb + 2] = acc[2]; dots[rb + 3] = acc[3];
    }
  }

  __syncthreads();                            // dots ready

  // 81 bilinear combines -> cbg[p][96] bf16 (192 B contiguous per pixel)
  if (tid < 96) {
    float c = 0.f;
    if (tid < DD2) {
      const int i = tid / DD, j = tid - i * DD;
      const float d00 = dots[j * PP + i];
      const float d01 = dots[j * PP + i + 1];
      const float d10 = dots[(j + 1) * PP + i];
      const float d11 = dots[(j + 1) * PP + i + 1];
      c = ((1.f - fy) * ((1.f - fx) * d00 + fx * d01) +
           fy * ((1.f - fx) * d10 + fx * d11)) * 0.0625f;   // 1/sqrt(256)
    }
    cbg[(size_t)p * 96 + tid] = (unsigned short)bf16rne(c);
  }
}

// ---------------- kernel 3: DAP as batched GEMM  out[96x4608] = W(96x96).CB ----------------
__global__ __launch_bounds__(64) void dap_gemm(
    const unsigned short* __restrict__ cbg, const unsigned short* __restrict__ Wf,
    float* __restrict__ out) {
  const int lane = threadIdx.x;
  const int hi = lane >> 4, lo = lane & 15;
  const int p0 = blockIdx.x * 16;

  short8v bq[3];
#pragma unroll
  for (int kt = 0; kt < 3; kt++)
    bq[kt] = *(const short8v*)(cbg + (size_t)(p0 + lo) * 96 + kt * 32 + hi * 8);

  f32x4 acc[6];
#pragma unroll
  for (int m = 0; m < 6; m++) acc[m] = (f32x4){0.f, 0.f, 0.f, 0.f};

#pragma unroll
  for (int m = 0; m < 6; m++) {
#pragma unroll
    for (int kt = 0; kt < 3; kt++) {
      short8v aw = *(const short8v*)(Wf + ((size_t)(m * 3 + kt) * 64 + lane) * 8);
      acc[m] = __builtin_amdgcn_mfma_f32_16x16x32_bf16(aw, bq[kt], acc[m], 0, 0, 0);
    }
  }

#pragma unroll
  for (int m = 0; m < 6; m++) {
#pragma unroll
    for (int j = 0; j < 4; j++) {
      const int o = m * 16 + hi * 4 + j;
      if (o < DD2) out[(size_t)o * HWSZ + p0 + lo] = acc[m][j];
    }
  }
}

extern "C" void kernel_launch(void* const* d_in, const int* in_sizes, int n_in,
                              void* d_out, int out_size, void* d_ws, size_t ws_size,
                              hipStream_t stream) {
  const float* f1     = (const float*)d_in[0];
  const float* f2     = (const float*)d_in[1];
  const float* coords = (const float*)d_in[2];
  const float* w_dap  = (const float*)d_in[3];
  float* out = (float*)d_out;

  // ws layout: [f2tb: HWSZ*512][zpage: 512][f1tb: HWSZ*512][Wf: 9216*2][cbg: HWSZ*96*2]
  char* f2tb  = (char*)d_ws;
  char* zpage = f2tb + (size_t)HWSZ * ROWB;
  char* f1tb  = zpage + 512;
  unsigned short* Wf  = (unsigned short*)(f1tb + (size_t)HWSZ * ROWB);
  unsigned short* cbg = Wf + 9216;

  dim3 tgrid((CC / 64) * (HWSZ / 64), 2);
  transpose_to_bf16<<<tgrid, 256, 0, stream>>>(f1, f2, w_dap, f2tb, f1tb, zpage, Wf);

  corr_main<<<dim3(HWSZ), 256, 0, stream>>>(f2tb, f1tb, coords, cbg);

  dap_gemm<<<dim3(HWSZ / 16), 64, 0, stream>>>(cbg, Wf, out);
}